// Round 3
// baseline (455.108 us; speedup 1.0000x reference)
//
#include <hip/hip_runtime.h>
#include <hip/hip_bf16.h>
#include <math.h>

// Problem constants (from reference)
#define B       64
#define S_VIT   257
#define S_Q     32
#define L       512
#define IMG     1408
#define HID     768
#define C       30000
#define H_CLUB  32
#define H_MINE  64

// ---------------------------------------------------------------------------
// Workspace layout (float offsets). Zeroed region = [0, WS_ZERO_FLOATS).
//   xv_sum : B*IMG     = 90112    (sum over S_VIT; scaled by 1/257 at use)
//   y_hist : B*C       = 1920000  (counts; scaled by 1/512 at use; exact ints)
//   dv     : B*H_MINE  = 4096     (atomic-accumulated partial dots)
//   dq     : B*H_MINE  = 4096
//   xq     : B*HID     = 49152
//   h_mu   : B*H_CLUB  = 2048
//   h_lv   : B*H_CLUB  = 2048
//   club_partial : 472 DOUBLES (fp64 — the fp32 reduction of ~35-magnitude
//                  grand total was the round-1 absmax failure: ~5e-6 error
//                  at grand-total level = 4e-8 at out level > 1-ulp threshold)
// ---------------------------------------------------------------------------
#define OFF_XVSUM   0
#define OFF_YHIST   (OFF_XVSUM + B * IMG)           // 90112
#define OFF_DV      (OFF_YHIST + B * C)             // 2010112
#define OFF_DQ      (OFF_DV + B * H_MINE)           // 2014208
#define WS_ZERO_FLOATS (OFF_DQ + B * H_MINE)        // 2018304
#define OFF_XQ      WS_ZERO_FLOATS                  // 2018304
#define OFF_HMU     (OFF_XQ + B * HID)              // 2067456
#define OFF_HLV     (OFF_HMU + B * H_CLUB)          // 2069504
#define OFF_CLUBP   (OFF_HLV + B * H_CLUB)          // 2071552 (byte off 8286208, 8-aligned)
#define N_CLUB_BLK_X 118
#define N_CLUB_BLK_Y 4
#define N_CLUB_PART (N_CLUB_BLK_X * N_CLUB_BLK_Y)   // 472

// ---------------------------------------------------------------------------
// K1: vit mean over S_VIT. grid (B, 8), block 256. float4 loads, atomic acc.
// fp32 is sufficient here: xv error ~8e-9/elem -> ~1e-9 at out level.
// ---------------------------------------------------------------------------
__global__ void k_vit_mean(const float* __restrict__ vit, float* __restrict__ xv_sum) {
    const int b     = blockIdx.x;
    const int split = blockIdx.y;
    const int tid   = threadIdx.x;
    const int s0 = split * 33;
    const int s1 = (s0 + 33 < S_VIT) ? s0 + 33 : S_VIT;
    const float4* row = (const float4*)(vit + (size_t)b * S_VIT * IMG);
    float4 a0 = make_float4(0.f, 0.f, 0.f, 0.f);
    float4 a1 = make_float4(0.f, 0.f, 0.f, 0.f);
    const bool second = (tid < 96);  // 352 float4 columns; 256 + 96
    for (int s = s0; s < s1; ++s) {
        const float4* p = row + (size_t)s * (IMG / 4);
        float4 v = p[tid];
        a0.x += v.x; a0.y += v.y; a0.z += v.z; a0.w += v.w;
        if (second) {
            float4 w = p[tid + 256];
            a1.x += w.x; a1.y += w.y; a1.z += w.z; a1.w += w.w;
        }
    }
    float* out = xv_sum + (size_t)b * IMG;
    atomicAdd(&out[tid * 4 + 0], a0.x);
    atomicAdd(&out[tid * 4 + 1], a0.y);
    atomicAdd(&out[tid * 4 + 2], a0.z);
    atomicAdd(&out[tid * 4 + 3], a0.w);
    if (second) {
        atomicAdd(&out[(tid + 256) * 4 + 0], a1.x);
        atomicAdd(&out[(tid + 256) * 4 + 1], a1.y);
        atomicAdd(&out[(tid + 256) * 4 + 2], a1.z);
        atomicAdd(&out[(tid + 256) * 4 + 3], a1.w);
    }
}

// ---------------------------------------------------------------------------
// K2: qformer mean (blocks 0..191) + label histogram scatter (blocks 192..199)
// hist counts are exact integers in fp32; /512 is a pow2 scale -> exact.
// ---------------------------------------------------------------------------
__global__ void k_xq_hist(const float* __restrict__ qf, const int* __restrict__ label,
                          float* __restrict__ xq, float* __restrict__ y_hist) {
    const int blk = blockIdx.x;
    const int tid = threadIdx.x;
    if (blk < 192) {
        const int o = blk * 256 + tid;            // < B*HID = 49152
        const int b = o / HID, k = o % HID;
        const float* base = qf + (size_t)b * S_Q * HID + k;
        float s = 0.f;
        #pragma unroll
        for (int t = 0; t < S_Q; ++t) s += base[(size_t)t * HID];
        xq[o] = s * (1.0f / (float)S_Q);
    } else {
        const int idx = (blk - 192) * 256 + tid;  // 0..2047
        for (int t = idx; t < B * L; t += 2048) {
            int lab = label[t];
            if (lab == -100) lab = 0;
            const int b = t >> 9;                 // t / L
            atomicAdd(&y_hist[(size_t)b * C + lab], 1.0f);
        }
    }
}

// ---------------------------------------------------------------------------
// K3: CLUB hidden layers: h_mu/h_lv = relu(xq @ W1 + b1). 8 blocks x 256.
// Double accumulation (free at this size); store fp32 (h err then ~1e-7,
// contributes ~1e-10 at out level).
// ---------------------------------------------------------------------------
__global__ void k_club_hidden(const float* __restrict__ xq,
                              const float* __restrict__ W_mu1, const float* __restrict__ b_mu1,
                              const float* __restrict__ W_lv1, const float* __restrict__ b_lv1,
                              float* __restrict__ h_mu, float* __restrict__ h_lv) {
    const int o = blockIdx.x * 256 + threadIdx.x;   // < B*H_CLUB = 2048
    const int b = o >> 5, h = o & 31;
    const float* x = xq + (size_t)b * HID;
    double am = (double)b_mu1[h], al = (double)b_lv1[h];
    for (int k = 0; k < HID; ++k) {
        const double xv = (double)x[k];
        am = fma(xv, (double)W_mu1[(size_t)k * H_CLUB + h], am);
        al = fma(xv, (double)W_lv1[(size_t)k * H_CLUB + h], al);
    }
    h_mu[o] = fmaxf((float)am, 0.f);
    h_lv[o] = fmaxf((float)al, 0.f);
}

// ---------------------------------------------------------------------------
// K4: CLUB main. grid (118, 4), block 256. Thread = one c; blockIdx.y = 16 b's.
// Per-term math in fp32 (errors ~1e-9 at out level, analyzed); the SUM is
// accumulated and reduced in fp64 — this was the round-1 precision fix.
// When y==yp==0 (29k of 30k c's per b): dn==dp exactly -> term == 0 exactly,
// matching the fp64 reference's analytic mu^2 cancellation.
// ---------------------------------------------------------------------------
__global__ void k_club_main(const float* __restrict__ W_mu2, const float* __restrict__ b_mu2,
                            const float* __restrict__ W_lv2, const float* __restrict__ b_lv2,
                            const float* __restrict__ h_mu, const float* __restrict__ h_lv,
                            const float* __restrict__ y_hist, const int* __restrict__ perm,
                            double* __restrict__ club_partial) {
    __shared__ float s_hmu[16 * H_CLUB];
    __shared__ float s_hlv[16 * H_CLUB];
    __shared__ int   s_perm[16];
    __shared__ double red[256];
    const int tid = threadIdx.x;
    const int c   = blockIdx.x * 256 + tid;
    const int b0  = blockIdx.y * 16;
    if (tid < 16) s_perm[tid] = perm[b0 + tid];
    for (int i = tid; i < 16 * H_CLUB; i += 256) {
        s_hmu[i] = h_mu[b0 * H_CLUB + i];
        s_hlv[i] = h_lv[b0 * H_CLUB + i];
    }
    __syncthreads();

    double total = 0.0;
    if (c < C) {
        float wm[H_CLUB], wl[H_CLUB];
        #pragma unroll
        for (int h = 0; h < H_CLUB; ++h) {
            wm[h] = W_mu2[(size_t)h * C + c];
            wl[h] = W_lv2[(size_t)h * C + c];
        }
        const float bm = b_mu2[c], bl = b_lv2[c];
        for (int bb = 0; bb < 16; ++bb) {
            float mu = bm, lv = bl;
            #pragma unroll
            for (int h = 0; h < H_CLUB; ++h) {
                mu = fmaf(s_hmu[bb * H_CLUB + h], wm[h], mu);
                lv = fmaf(s_hlv[bb * H_CLUB + h], wl[h], lv);
            }
            const float th = tanhf(lv);
            const float iv = 1.0f / (expf(th) + 1e-6f);
            const int b = b0 + bb;
            const float y  = y_hist[(size_t)b * C + c] * (1.0f / (float)L);
            const float yp = y_hist[(size_t)s_perm[bb] * C + c] * (1.0f / (float)L);
            const float dn = mu - yp;
            const float dp = mu - y;
            total += (double)(iv * (dn * dn - dp * dp));
        }
    }
    red[tid] = total;
    __syncthreads();
    for (int off = 128; off > 0; off >>= 1) {
        if (tid < off) red[tid] += red[tid + off];
        __syncthreads();
    }
    if (tid == 0) club_partial[blockIdx.y * gridDim.x + blockIdx.x] = red[0];
}

// ---------------------------------------------------------------------------
// K5: MINE first layer partial dots. grid (16, 4), block 256.
// dv[b,j] = (xv_sum[b,:]/257) @ W_t1[:IMG, j];  dq[b,j] = xq[b,:] @ W_t1[IMG:, j]
// fp32 sufficient (dv/dq errors ~2e-8 -> ~3e-9 on T -> ~3e-10 at out level).
// ---------------------------------------------------------------------------
__global__ void k_mine_dot(const float* __restrict__ xv_sum, const float* __restrict__ xq,
                           const float* __restrict__ W_t1,
                           float* __restrict__ dv, float* __restrict__ dq) {
    const int o = blockIdx.x * 256 + threadIdx.x;   // < B*H_MINE = 4096
    const int b = o >> 6, j = o & 63;
    const int q = blockIdx.y;                       // 0..3
    const float* xvb = xv_sum + (size_t)b * IMG;
    float accv = 0.f;
    for (int i = q * (IMG / 4); i < (q + 1) * (IMG / 4); ++i)
        accv = fmaf(xvb[i], W_t1[(size_t)i * H_MINE + j], accv);
    atomicAdd(&dv[o], accv * (1.0f / (float)S_VIT));
    const float* xqb = xq + (size_t)b * HID;
    float accq = 0.f;
    for (int k = q * (HID / 4); k < (q + 1) * (HID / 4); ++k)
        accq = fmaf(xqb[k], W_t1[(size_t)(IMG + k) * H_MINE + j], accq);
    atomicAdd(&dq[o], accq);
}

// ---------------------------------------------------------------------------
// K6: final. 1 block x 256. All scalar combination math in fp64.
// ---------------------------------------------------------------------------
__global__ void k_final(const float* __restrict__ dv, const float* __restrict__ dq,
                        const float* __restrict__ b_t1, const float* __restrict__ W_t2,
                        const float* __restrict__ b_t2, const int* __restrict__ rand_idx,
                        const double* __restrict__ club_partial,
                        float* __restrict__ out) {
    __shared__ double sT0[B];
    __shared__ double sT1[B];
    __shared__ double red[256];
    const int tid = threadIdx.x;
    double cp = 0.0;
    for (int i = tid; i < N_CLUB_PART; i += 256) cp += club_partial[i];
    red[tid] = cp;
    __syncthreads();
    for (int off = 128; off > 0; off >>= 1) {
        if (tid < off) red[tid] += red[tid + off];
        __syncthreads();
    }
    const double club_total = red[0];

    if (tid < B) {
        const int b  = tid;
        const int rb = rand_idx[b];
        double a0 = 0.0, a1 = 0.0;
        for (int j = 0; j < H_MINE; ++j) {
            const double base_v = (double)dv[b * H_MINE + j] + (double)b_t1[j];
            const double v0 = base_v + (double)dq[b * H_MINE + j];
            const double v1 = base_v + (double)dq[rb * H_MINE + j];
            const double w = (double)W_t2[j];
            a0 = fma(fmax(v0, 0.0), w, a0);
            a1 = fma(fmax(v1, 0.0), w, a1);
        }
        sT0[b] = a0 + (double)b_t2[0];
        sT1[b] = a1 + (double)b_t2[0];
    }
    __syncthreads();
    if (tid == 0) {
        double mean0 = 0.0, mx = -1e300;
        for (int b = 0; b < B; ++b) {
            mean0 += sT0[b];
            mx = fmax(mx, sT1[b]);
        }
        mean0 *= (1.0 / (double)B);
        double se = 0.0;
        for (int b = 0; b < B; ++b) se += exp(sT1[b] - mx);
        const double lse  = mx + log(se);
        const double I_xz = mean0 - (lse - log((double)B));
        const double I_zy = club_total / (2.0 * (double)B);
        out[0] = (float)(I_zy - 0.1 * I_xz);
    }
}

// ---------------------------------------------------------------------------
extern "C" void kernel_launch(void* const* d_in, const int* in_sizes, int n_in,
                              void* d_out, int out_size, void* d_ws, size_t ws_size,
                              hipStream_t stream) {
    const float* vit     = (const float*)d_in[0];
    const float* qformer = (const float*)d_in[1];
    const int*   label   = (const int*)d_in[2];
    const int*   perm    = (const int*)d_in[3];
    const int*   randi   = (const int*)d_in[4];
    const float* W_mu1   = (const float*)d_in[5];
    const float* b_mu1   = (const float*)d_in[6];
    const float* W_mu2   = (const float*)d_in[7];
    const float* b_mu2   = (const float*)d_in[8];
    const float* W_lv1   = (const float*)d_in[9];
    const float* b_lv1   = (const float*)d_in[10];
    const float* W_lv2   = (const float*)d_in[11];
    const float* b_lv2   = (const float*)d_in[12];
    const float* W_t1    = (const float*)d_in[13];
    const float* b_t1    = (const float*)d_in[14];
    const float* W_t2    = (const float*)d_in[15];
    const float* b_t2    = (const float*)d_in[16];

    float* ws      = (float*)d_ws;
    float* xv_sum  = ws + OFF_XVSUM;
    float* y_hist  = ws + OFF_YHIST;
    float* dv      = ws + OFF_DV;
    float* dq      = ws + OFF_DQ;
    float* xq      = ws + OFF_XQ;
    float* h_mu    = ws + OFF_HMU;
    float* h_lv    = ws + OFF_HLV;
    double* club_p = (double*)(ws + OFF_CLUBP);

    // Zero accumulation buffers (xv_sum, y_hist, dv, dq) in one memset.
    hipMemsetAsync(ws, 0, (size_t)WS_ZERO_FLOATS * sizeof(float), stream);

    k_vit_mean<<<dim3(B, 8), 256, 0, stream>>>(vit, xv_sum);
    k_xq_hist<<<200, 256, 0, stream>>>(qformer, label, xq, y_hist);
    k_club_hidden<<<8, 256, 0, stream>>>(xq, W_mu1, b_mu1, W_lv1, b_lv1, h_mu, h_lv);
    k_club_main<<<dim3(N_CLUB_BLK_X, N_CLUB_BLK_Y), 256, 0, stream>>>(
        W_mu2, b_mu2, W_lv2, b_lv2, h_mu, h_lv, y_hist, perm, club_p);
    k_mine_dot<<<dim3(16, 4), 256, 0, stream>>>(xv_sum, xq, W_t1, dv, dq);
    k_final<<<1, 256, 0, stream>>>(dv, dq, b_t1, W_t2, b_t2, randi, club_p, (float*)d_out);
}

// Round 4
// 303.282 us; speedup vs baseline: 1.5006x; 1.5006x over previous
//
#include <hip/hip_runtime.h>
#include <hip/hip_bf16.h>
#include <math.h>

// Problem constants (from reference)
#define B       64
#define S_VIT   257
#define S_Q     32
#define L       512
#define IMG     1408
#define HID     768
#define C       30000
#define H_CLUB  32
#define H_MINE  64

// ---------------------------------------------------------------------------
// Workspace layout (float offsets). Zeroed region = [0, WS_ZERO_FLOATS).
//   xv_sum : B*IMG     = 90112 fp32  (atomic sum over S_VIT; /257 at use)
//   y_hist : B*C       = 1920000 fp32 (counts; /512 at use; exact ints)
//   xq     : B*HID     = 49152 fp32
//   h_mu   : B*H_CLUB  = 2048 fp32
//   h_lv   : B*H_CLUB  = 2048 fp32
//   dv64   : B*H_MINE  = 4096 fp64  (written whole by k_mine_dot, no zeroing)
//   dq64   : B*H_MINE  = 4096 fp64
//   club_partial : 472 fp64 (fp32 reduction of the ~35-magnitude grand total
//                  was the round-1 absmax failure; fp64 fixed it — round 3
//                  passed at absmax 2.98e-8 vs 3.23e-8. CLUB summation
//                  structure is now frozen: do not reorder.)
// ---------------------------------------------------------------------------
#define OFF_XVSUM   0
#define OFF_YHIST   (OFF_XVSUM + B * IMG)            // 90112
#define WS_ZERO_FLOATS (OFF_YHIST + B * C)           // 2010112 (only these need 0)
#define OFF_XQ      WS_ZERO_FLOATS                   // 2010112
#define OFF_HMU     (OFF_XQ + B * HID)               // 2059264
#define OFF_HLV     (OFF_HMU + B * H_CLUB)           // 2061312
#define OFF_DV64    (OFF_HLV + B * H_CLUB)           // 2063360 (even -> 8B aligned)
#define OFF_DQ64    (OFF_DV64 + 2 * B * H_MINE)      // 2071552
#define OFF_CLUBP   (OFF_DQ64 + 2 * B * H_MINE)      // 2079744 (even -> 8B aligned)
#define N_CLUB_BLK_X 118
#define N_CLUB_BLK_Y 4
#define N_CLUB_PART (N_CLUB_BLK_X * N_CLUB_BLK_Y)    // 472

// ---------------------------------------------------------------------------
// K1: vit mean over S_VIT. grid (B, 8), block 256. float4 loads, atomic acc.
// 512 blocks, 8 waves/CU, streaming 92.6 MB -> near HBM-bound. UNCHANGED.
// ---------------------------------------------------------------------------
__global__ void k_vit_mean(const float* __restrict__ vit, float* __restrict__ xv_sum) {
    const int b     = blockIdx.x;
    const int split = blockIdx.y;
    const int tid   = threadIdx.x;
    const int s0 = split * 33;
    const int s1 = (s0 + 33 < S_VIT) ? s0 + 33 : S_VIT;
    const float4* row = (const float4*)(vit + (size_t)b * S_VIT * IMG);
    float4 a0 = make_float4(0.f, 0.f, 0.f, 0.f);
    float4 a1 = make_float4(0.f, 0.f, 0.f, 0.f);
    const bool second = (tid < 96);  // 352 float4 columns; 256 + 96
    for (int s = s0; s < s1; ++s) {
        const float4* p = row + (size_t)s * (IMG / 4);
        float4 v = p[tid];
        a0.x += v.x; a0.y += v.y; a0.z += v.z; a0.w += v.w;
        if (second) {
            float4 w = p[tid + 256];
            a1.x += w.x; a1.y += w.y; a1.z += w.z; a1.w += w.w;
        }
    }
    float* out = xv_sum + (size_t)b * IMG;
    atomicAdd(&out[tid * 4 + 0], a0.x);
    atomicAdd(&out[tid * 4 + 1], a0.y);
    atomicAdd(&out[tid * 4 + 2], a0.z);
    atomicAdd(&out[tid * 4 + 3], a0.w);
    if (second) {
        atomicAdd(&out[(tid + 256) * 4 + 0], a1.x);
        atomicAdd(&out[(tid + 256) * 4 + 1], a1.y);
        atomicAdd(&out[(tid + 256) * 4 + 2], a1.z);
        atomicAdd(&out[(tid + 256) * 4 + 3], a1.w);
    }
}

// ---------------------------------------------------------------------------
// K2: qformer mean (blocks 0..191) + label histogram scatter (192..199).
// UNCHANGED (numerics frozen; feeds the tight CLUB path).
// ---------------------------------------------------------------------------
__global__ void k_xq_hist(const float* __restrict__ qf, const int* __restrict__ label,
                          float* __restrict__ xq, float* __restrict__ y_hist) {
    const int blk = blockIdx.x;
    const int tid = threadIdx.x;
    if (blk < 192) {
        const int o = blk * 256 + tid;            // < B*HID = 49152
        const int b = o / HID, k = o % HID;
        const float* base = qf + (size_t)b * S_Q * HID + k;
        float s = 0.f;
        #pragma unroll
        for (int t = 0; t < S_Q; ++t) s += base[(size_t)t * HID];
        xq[o] = s * (1.0f / (float)S_Q);
    } else {
        const int idx = (blk - 192) * 256 + tid;  // 0..2047
        for (int t = idx; t < B * L; t += 2048) {
            int lab = label[t];
            if (lab == -100) lab = 0;
            const int b = t >> 9;                 // t / L
            atomicAdd(&y_hist[(size_t)b * C + lab], 1.0f);
        }
    }
}

// ---------------------------------------------------------------------------
// K3 v2: CLUB hidden layers. Round-3 version had 8 blocks x 768 SERIAL fp64
// dependent-load iterations (1 wave/SIMD, ~100 us latency-bound). Now:
// grid B=64 (block per b), 256 threads = h(32) x kk(8); each thread covers a
// contiguous 96-wide K chunk with 4 independent fp64 accumulators (ILP 4),
// LDS tree over kk, bias+relu+fp32 store. fp64 reassociation moves h by
// ~1e-16 rel -> fp32-stored h bit-identical -> CLUB numerics preserved.
// ---------------------------------------------------------------------------
__global__ void k_club_hidden(const float* __restrict__ xq,
                              const float* __restrict__ W_mu1, const float* __restrict__ b_mu1,
                              const float* __restrict__ W_lv1, const float* __restrict__ b_lv1,
                              float* __restrict__ h_mu, float* __restrict__ h_lv) {
    __shared__ double s_mu[8][H_CLUB];
    __shared__ double s_lv[8][H_CLUB];
    const int b  = blockIdx.x;
    const int h  = threadIdx.x & 31;
    const int kk = threadIdx.x >> 5;    // 0..7
    const float* x = xq + (size_t)b * HID;
    const int k0 = kk * 96;
    double m0 = 0, m1 = 0, m2 = 0, m3 = 0;
    double l0 = 0, l1 = 0, l2 = 0, l3 = 0;
    #pragma unroll 4
    for (int t = 0; t < 96; t += 4) {
        const int k = k0 + t;
        const double x0 = (double)x[k], x1 = (double)x[k + 1];
        const double x2 = (double)x[k + 2], x3 = (double)x[k + 3];
        m0 = fma(x0, (double)W_mu1[(size_t)(k)     * H_CLUB + h], m0);
        m1 = fma(x1, (double)W_mu1[(size_t)(k + 1) * H_CLUB + h], m1);
        m2 = fma(x2, (double)W_mu1[(size_t)(k + 2) * H_CLUB + h], m2);
        m3 = fma(x3, (double)W_mu1[(size_t)(k + 3) * H_CLUB + h], m3);
        l0 = fma(x0, (double)W_lv1[(size_t)(k)     * H_CLUB + h], l0);
        l1 = fma(x1, (double)W_lv1[(size_t)(k + 1) * H_CLUB + h], l1);
        l2 = fma(x2, (double)W_lv1[(size_t)(k + 2) * H_CLUB + h], l2);
        l3 = fma(x3, (double)W_lv1[(size_t)(k + 3) * H_CLUB + h], l3);
    }
    s_mu[kk][h] = (m0 + m1) + (m2 + m3);
    s_lv[kk][h] = (l0 + l1) + (l2 + l3);
    __syncthreads();
    if (threadIdx.x < 32) {
        const int hh = threadIdx.x;
        double am = (double)b_mu1[hh], al = (double)b_lv1[hh];
        #pragma unroll
        for (int i = 0; i < 8; ++i) { am += s_mu[i][hh]; al += s_lv[i][hh]; }
        h_mu[b * H_CLUB + hh] = fmaxf((float)am, 0.f);
        h_lv[b * H_CLUB + hh] = fmaxf((float)al, 0.f);
    }
}

// ---------------------------------------------------------------------------
// K4: CLUB main. UNCHANGED — summation structure frozen (absmax margin 8%).
// ---------------------------------------------------------------------------
__global__ void k_club_main(const float* __restrict__ W_mu2, const float* __restrict__ b_mu2,
                            const float* __restrict__ W_lv2, const float* __restrict__ b_lv2,
                            const float* __restrict__ h_mu, const float* __restrict__ h_lv,
                            const float* __restrict__ y_hist, const int* __restrict__ perm,
                            double* __restrict__ club_partial) {
    __shared__ float s_hmu[16 * H_CLUB];
    __shared__ float s_hlv[16 * H_CLUB];
    __shared__ int   s_perm[16];
    __shared__ double red[256];
    const int tid = threadIdx.x;
    const int c   = blockIdx.x * 256 + tid;
    const int b0  = blockIdx.y * 16;
    if (tid < 16) s_perm[tid] = perm[b0 + tid];
    for (int i = tid; i < 16 * H_CLUB; i += 256) {
        s_hmu[i] = h_mu[b0 * H_CLUB + i];
        s_hlv[i] = h_lv[b0 * H_CLUB + i];
    }
    __syncthreads();

    double total = 0.0;
    if (c < C) {
        float wm[H_CLUB], wl[H_CLUB];
        #pragma unroll
        for (int h = 0; h < H_CLUB; ++h) {
            wm[h] = W_mu2[(size_t)h * C + c];
            wl[h] = W_lv2[(size_t)h * C + c];
        }
        const float bm = b_mu2[c], bl = b_lv2[c];
        for (int bb = 0; bb < 16; ++bb) {
            float mu = bm, lv = bl;
            #pragma unroll
            for (int h = 0; h < H_CLUB; ++h) {
                mu = fmaf(s_hmu[bb * H_CLUB + h], wm[h], mu);
                lv = fmaf(s_hlv[bb * H_CLUB + h], wl[h], lv);
            }
            const float th = tanhf(lv);
            const float iv = 1.0f / (expf(th) + 1e-6f);
            const int b = b0 + bb;
            const float y  = y_hist[(size_t)b * C + c] * (1.0f / (float)L);
            const float yp = y_hist[(size_t)s_perm[bb] * C + c] * (1.0f / (float)L);
            const float dn = mu - yp;
            const float dp = mu - y;
            total += (double)(iv * (dn * dn - dp * dp));
        }
    }
    red[tid] = total;
    __syncthreads();
    for (int off = 128; off > 0; off >>= 1) {
        if (tid < off) red[tid] += red[tid + off];
        __syncthreads();
    }
    if (tid == 0) club_partial[blockIdx.y * gridDim.x + blockIdx.x] = red[0];
}

// ---------------------------------------------------------------------------
// K5 v2: MINE first layer. Round-3 version: 64 blocks, 544 serial
// dependent-load iters/thread, VGPR=8, 1 wave/SIMD -> 183 us latency-bound.
// Now: grid B=64, block 512 = j(64) x kk(8); contiguous K chunks per thread
// (176 of IMG, 96 of HID), 4 independent fp64 accumulators (chain 44->11),
// LDS reduce over kk, direct fp64 store (no atomics, no zero-init).
// ---------------------------------------------------------------------------
__global__ void k_mine_dot(const float* __restrict__ xv_sum, const float* __restrict__ xq,
                           const float* __restrict__ W_t1,
                           double* __restrict__ dv, double* __restrict__ dq) {
    __shared__ double s_v[8][H_MINE];
    __shared__ double s_q[8][H_MINE];
    const int b  = blockIdx.x;
    const int j  = threadIdx.x & 63;
    const int kk = threadIdx.x >> 6;    // 0..7
    const float* xvb = xv_sum + (size_t)b * IMG;
    const float* xqb = xq + (size_t)b * HID;

    double a0 = 0, a1 = 0, a2 = 0, a3 = 0;
    {
        const int k0 = kk * (IMG / 8);  // 176-wide chunk
        #pragma unroll 4
        for (int t = 0; t < IMG / 8; t += 4) {
            const int k = k0 + t;
            a0 = fma((double)xvb[k],     (double)W_t1[(size_t)(k)     * H_MINE + j], a0);
            a1 = fma((double)xvb[k + 1], (double)W_t1[(size_t)(k + 1) * H_MINE + j], a1);
            a2 = fma((double)xvb[k + 2], (double)W_t1[(size_t)(k + 2) * H_MINE + j], a2);
            a3 = fma((double)xvb[k + 3], (double)W_t1[(size_t)(k + 3) * H_MINE + j], a3);
        }
    }
    s_v[kk][j] = (a0 + a1) + (a2 + a3);

    double q0 = 0, q1 = 0, q2 = 0, q3 = 0;
    {
        const int k0 = kk * (HID / 8);  // 96-wide chunk
        #pragma unroll 4
        for (int t = 0; t < HID / 8; t += 4) {
            const int k = k0 + t;
            q0 = fma((double)xqb[k],     (double)W_t1[(size_t)(IMG + k)     * H_MINE + j], q0);
            q1 = fma((double)xqb[k + 1], (double)W_t1[(size_t)(IMG + k + 1) * H_MINE + j], q1);
            q2 = fma((double)xqb[k + 2], (double)W_t1[(size_t)(IMG + k + 2) * H_MINE + j], q2);
            q3 = fma((double)xqb[k + 3], (double)W_t1[(size_t)(IMG + k + 3) * H_MINE + j], q3);
        }
    }
    s_q[kk][j] = (q0 + q1) + (q2 + q3);
    __syncthreads();
    if (threadIdx.x < 64) {
        const int jj = threadIdx.x;
        double sv = 0, sq = 0;
        #pragma unroll
        for (int i = 0; i < 8; ++i) { sv += s_v[i][jj]; sq += s_q[i][jj]; }
        dv[b * H_MINE + jj] = sv * (1.0 / (double)S_VIT);
        dq[b * H_MINE + jj] = sq;
    }
}

// ---------------------------------------------------------------------------
// K6: final. 1 block x 256. All scalar combination math in fp64.
// dv/dq now fp64 (more accurate than round 3). CLUB reduction unchanged.
// ---------------------------------------------------------------------------
__global__ void k_final(const double* __restrict__ dv, const double* __restrict__ dq,
                        const float* __restrict__ b_t1, const float* __restrict__ W_t2,
                        const float* __restrict__ b_t2, const int* __restrict__ rand_idx,
                        const double* __restrict__ club_partial,
                        float* __restrict__ out) {
    __shared__ double sT0[B];
    __shared__ double sT1[B];
    __shared__ double red[256];
    const int tid = threadIdx.x;
    double cp = 0.0;
    for (int i = tid; i < N_CLUB_PART; i += 256) cp += club_partial[i];
    red[tid] = cp;
    __syncthreads();
    for (int off = 128; off > 0; off >>= 1) {
        if (tid < off) red[tid] += red[tid + off];
        __syncthreads();
    }
    const double club_total = red[0];

    if (tid < B) {
        const int b  = tid;
        const int rb = rand_idx[b];
        double a0 = 0.0, a1 = 0.0;
        for (int j = 0; j < H_MINE; ++j) {
            const double base_v = dv[b * H_MINE + j] + (double)b_t1[j];
            const double v0 = base_v + dq[b * H_MINE + j];
            const double v1 = base_v + dq[rb * H_MINE + j];
            const double w = (double)W_t2[j];
            a0 = fma(fmax(v0, 0.0), w, a0);
            a1 = fma(fmax(v1, 0.0), w, a1);
        }
        sT0[b] = a0 + (double)b_t2[0];
        sT1[b] = a1 + (double)b_t2[0];
    }
    __syncthreads();
    if (tid == 0) {
        double mean0 = 0.0, mx = -1e300;
        for (int b = 0; b < B; ++b) {
            mean0 += sT0[b];
            mx = fmax(mx, sT1[b]);
        }
        mean0 *= (1.0 / (double)B);
        double se = 0.0;
        for (int b = 0; b < B; ++b) se += exp(sT1[b] - mx);
        const double lse  = mx + log(se);
        const double I_xz = mean0 - (lse - log((double)B));
        const double I_zy = club_total / (2.0 * (double)B);
        out[0] = (float)(I_zy - 0.1 * I_xz);
    }
}

// ---------------------------------------------------------------------------
extern "C" void kernel_launch(void* const* d_in, const int* in_sizes, int n_in,
                              void* d_out, int out_size, void* d_ws, size_t ws_size,
                              hipStream_t stream) {
    const float* vit     = (const float*)d_in[0];
    const float* qformer = (const float*)d_in[1];
    const int*   label   = (const int*)d_in[2];
    const int*   perm    = (const int*)d_in[3];
    const int*   randi   = (const int*)d_in[4];
    const float* W_mu1   = (const float*)d_in[5];
    const float* b_mu1   = (const float*)d_in[6];
    const float* W_mu2   = (const float*)d_in[7];
    const float* b_mu2   = (const float*)d_in[8];
    const float* W_lv1   = (const float*)d_in[9];
    const float* b_lv1   = (const float*)d_in[10];
    const float* W_lv2   = (const float*)d_in[11];
    const float* b_lv2   = (const float*)d_in[12];
    const float* W_t1    = (const float*)d_in[13];
    const float* b_t1    = (const float*)d_in[14];
    const float* W_t2    = (const float*)d_in[15];
    const float* b_t2    = (const float*)d_in[16];

    float* ws      = (float*)d_ws;
    float* xv_sum  = ws + OFF_XVSUM;
    float* y_hist  = ws + OFF_YHIST;
    float* xq      = ws + OFF_XQ;
    float* h_mu    = ws + OFF_HMU;
    float* h_lv    = ws + OFF_HLV;
    double* dv64   = (double*)(ws + OFF_DV64);
    double* dq64   = (double*)(ws + OFF_DQ64);
    double* club_p = (double*)(ws + OFF_CLUBP);

    // Zero only the atomic-accumulated buffers (xv_sum, y_hist).
    hipMemsetAsync(ws, 0, (size_t)WS_ZERO_FLOATS * sizeof(float), stream);

    k_vit_mean<<<dim3(B, 8), 256, 0, stream>>>(vit, xv_sum);
    k_xq_hist<<<200, 256, 0, stream>>>(qformer, label, xq, y_hist);
    k_club_hidden<<<B, 256, 0, stream>>>(xq, W_mu1, b_mu1, W_lv1, b_lv1, h_mu, h_lv);
    k_club_main<<<dim3(N_CLUB_BLK_X, N_CLUB_BLK_Y), 256, 0, stream>>>(
        W_mu2, b_mu2, W_lv2, b_lv2, h_mu, h_lv, y_hist, perm, club_p);
    k_mine_dot<<<B, 512, 0, stream>>>(xv_sum, xq, W_t1, dv64, dq64);
    k_final<<<1, 256, 0, stream>>>(dv64, dq64, b_t1, W_t2, b_t2, randi, club_p, (float*)d_out);
}

// Round 5
// 220.942 us; speedup vs baseline: 2.0599x; 1.3727x over previous
//
#include <hip/hip_runtime.h>
#include <hip/hip_bf16.h>
#include <math.h>

// Problem constants (from reference)
#define B       64
#define S_VIT   257
#define S_Q     32
#define L       512
#define IMG     1408
#define HID     768
#define C       30000
#define H_CLUB  32
#define H_MINE  64

// ---------------------------------------------------------------------------
// Workspace layout (float offsets). Zeroed region = [0, WS_ZERO_FLOATS).
//   xv_sum : B*IMG  fp32 (atomic sum over S_VIT; /257 at use)
//   y_hist : B*C    fp32 (counts; /512 at use; exact ints, order-independent)
//   dv64   : B*H_MINE fp64 (atomic fp64 accumulation -> needs zeroing)
//   dq64   : B*H_MINE fp64
//   xq     : B*HID  fp32
//   h_mu/h_lv : B*H_CLUB fp32
//   club_partial : 472 fp64  (CLUB summation structure FROZEN since round 3:
//                  absmax 2.98e-8 vs threshold 3.23e-8, only 8% margin.)
// ---------------------------------------------------------------------------
#define OFF_XVSUM   0
#define OFF_YHIST   (OFF_XVSUM + B * IMG)            // 90112
#define OFF_DV64    (OFF_YHIST + B * C)              // 2010112 (even -> 8B aligned)
#define OFF_DQ64    (OFF_DV64 + 2 * B * H_MINE)      // 2018304
#define WS_ZERO_FLOATS (OFF_DQ64 + 2 * B * H_MINE)   // 2026496
#define OFF_XQ      WS_ZERO_FLOATS                   // 2026496
#define OFF_HMU     (OFF_XQ + B * HID)               // 2075648
#define OFF_HLV     (OFF_HMU + B * H_CLUB)           // 2077696
#define OFF_CLUBP   (OFF_HLV + B * H_CLUB)           // 2079744 (even -> 8B aligned)
#define N_CLUB_BLK_X 118
#define N_CLUB_BLK_Y 4
#define N_CLUB_PART (N_CLUB_BLK_X * N_CLUB_BLK_Y)    // 472

// ---------------------------------------------------------------------------
// Stage A: vit mean (blocks 0..511) + xq mean float4 (512..559) + hist (560..567).
// All three independent; merged to cut graph nodes / launch gaps.
// xq per-element summation order identical to round-4 (t ascending) -> xq
// bit-identical -> CLUB path preserved.
// ---------------------------------------------------------------------------
__global__ void k_stage_a(const float* __restrict__ vit, const float* __restrict__ qf,
                          const int* __restrict__ label,
                          float* __restrict__ xv_sum, float* __restrict__ xq,
                          float* __restrict__ y_hist) {
    const int blk = blockIdx.x;
    const int tid = threadIdx.x;
    if (blk < 512) {
        // ---- vit mean over S_VIT; (b, split) covers 33-ish rows of 352 float4
        const int b     = blk >> 3;
        const int split = blk & 7;
        const int s0 = split * 33;
        const int s1 = (s0 + 33 < S_VIT) ? s0 + 33 : S_VIT;
        const float4* row = (const float4*)(vit + (size_t)b * S_VIT * IMG);
        float4 a0 = make_float4(0.f, 0.f, 0.f, 0.f);
        float4 a1 = make_float4(0.f, 0.f, 0.f, 0.f);
        const bool second = (tid < 96);  // 352 float4 columns; 256 + 96
        for (int s = s0; s < s1; ++s) {
            const float4* p = row + (size_t)s * (IMG / 4);
            float4 v = p[tid];
            a0.x += v.x; a0.y += v.y; a0.z += v.z; a0.w += v.w;
            if (second) {
                float4 w = p[tid + 256];
                a1.x += w.x; a1.y += w.y; a1.z += w.z; a1.w += w.w;
            }
        }
        float* out = xv_sum + (size_t)b * IMG;
        atomicAdd(&out[tid * 4 + 0], a0.x);
        atomicAdd(&out[tid * 4 + 1], a0.y);
        atomicAdd(&out[tid * 4 + 2], a0.z);
        atomicAdd(&out[tid * 4 + 3], a0.w);
        if (second) {
            atomicAdd(&out[(tid + 256) * 4 + 0], a1.x);
            atomicAdd(&out[(tid + 256) * 4 + 1], a1.y);
            atomicAdd(&out[(tid + 256) * 4 + 2], a1.z);
            atomicAdd(&out[(tid + 256) * 4 + 3], a1.w);
        }
    } else if (blk < 560) {
        // ---- qformer mean, float4-vectorized. 48 blocks x 256 = 12288 float4s
        const int idx = (blk - 512) * 256 + tid;       // < B*HID/4
        const int b  = idx / (HID / 4);
        const int k4 = idx % (HID / 4);
        const float* base = qf + (size_t)b * S_Q * HID + k4 * 4;
        float4 s = make_float4(0.f, 0.f, 0.f, 0.f);
        #pragma unroll
        for (int t = 0; t < S_Q; ++t) {
            const float4 v = *(const float4*)(base + (size_t)t * HID);
            s.x += v.x; s.y += v.y; s.z += v.z; s.w += v.w;
        }
        const float inv = 1.0f / (float)S_Q;
        s.x *= inv; s.y *= inv; s.z *= inv; s.w *= inv;
        ((float4*)xq)[(size_t)b * (HID / 4) + k4] = s;
    } else {
        // ---- label histogram scatter (exact integer counts)
        const int idx = (blk - 560) * 256 + tid;       // 0..2047
        for (int t = idx; t < B * L; t += 2048) {
            int lab = label[t];
            if (lab == -100) lab = 0;
            const int b = t >> 9;                      // t / L
            atomicAdd(&y_hist[(size_t)b * C + lab], 1.0f);
        }
    }
}

// ---------------------------------------------------------------------------
// Stage B: MINE first-layer dots (blocks 0..255) + CLUB hidden (256..319).
// Round-4 failure mode: VGPR_Count=28 -> compiler serialized every load at
// full memory latency (68.8 us at 0.58% VALUBusy). Now: float4 weight loads,
// explicit ILP chains, launch_bounds to unlock registers, 5x more blocks.
// ---------------------------------------------------------------------------
__global__ void __launch_bounds__(256, 2)
k_stage_b(const float* __restrict__ xv_sum, const float* __restrict__ xq,
          const float* __restrict__ W_t1,
          const float* __restrict__ W_mu1, const float* __restrict__ b_mu1,
          const float* __restrict__ W_lv1, const float* __restrict__ b_lv1,
          double* __restrict__ dv, double* __restrict__ dq,
          float* __restrict__ h_mu, float* __restrict__ h_lv) {
    const int blk = blockIdx.x;
    const int tid = threadIdx.x;
    if (blk < 256) {
        // ---- MINE: block = (b, quarter q). threads = j(64) x kk(4).
        __shared__ double s_v[4][H_MINE];
        __shared__ double s_q[4][H_MINE];
        const int b  = blk >> 2;
        const int q  = blk & 3;
        const int j  = tid & 63;
        const int kk = tid >> 6;                       // 0..3
        const float* xvb = xv_sum + (size_t)b * IMG;
        const float* xqb = xq + (size_t)b * HID;

        double a0 = 0, a1 = 0, a2 = 0, a3 = 0;
        {
            const int k0 = q * (IMG / 4) + kk * (IMG / 16);   // 88-wide chunk
            #pragma unroll 2
            for (int t = 0; t < IMG / 16; t += 4) {
                const int k = k0 + t;
                a0 = fma((double)xvb[k],     (double)W_t1[(size_t)(k)     * H_MINE + j], a0);
                a1 = fma((double)xvb[k + 1], (double)W_t1[(size_t)(k + 1) * H_MINE + j], a1);
                a2 = fma((double)xvb[k + 2], (double)W_t1[(size_t)(k + 2) * H_MINE + j], a2);
                a3 = fma((double)xvb[k + 3], (double)W_t1[(size_t)(k + 3) * H_MINE + j], a3);
            }
        }
        s_v[kk][j] = (a0 + a1) + (a2 + a3);

        double q0 = 0, q1 = 0, q2 = 0, q3 = 0;
        {
            const int k0 = q * (HID / 4) + kk * (HID / 16);   // 48-wide chunk
            #pragma unroll 2
            for (int t = 0; t < HID / 16; t += 4) {
                const int k = k0 + t;
                q0 = fma((double)xqb[k],     (double)W_t1[(size_t)(IMG + k)     * H_MINE + j], q0);
                q1 = fma((double)xqb[k + 1], (double)W_t1[(size_t)(IMG + k + 1) * H_MINE + j], q1);
                q2 = fma((double)xqb[k + 2], (double)W_t1[(size_t)(IMG + k + 2) * H_MINE + j], q2);
                q3 = fma((double)xqb[k + 3], (double)W_t1[(size_t)(IMG + k + 3) * H_MINE + j], q3);
            }
        }
        s_q[kk][j] = (q0 + q1) + (q2 + q3);
        __syncthreads();
        if (tid < H_MINE) {
            double sv = (s_v[0][tid] + s_v[1][tid]) + (s_v[2][tid] + s_v[3][tid]);
            double sq = (s_q[0][tid] + s_q[1][tid]) + (s_q[2][tid] + s_q[3][tid]);
            atomicAdd(&dv[b * H_MINE + tid], sv * (1.0 / (double)S_VIT));
            atomicAdd(&dq[b * H_MINE + tid], sq);
        }
    } else {
        // ---- CLUB hidden: block per b. threads = h4(8) x kk(32); each thread
        // does a 24-k chunk for 4 h's via float4 weight loads (coalesced 128B
        // rows), 8 independent fp64 chains. xq staged in LDS (broadcast).
        __shared__ float  sx[HID];
        __shared__ double s_mu[32][H_CLUB];
        __shared__ double s_lv[32][H_CLUB];
        const int b = blk - 256;
        for (int i = tid; i < HID; i += 256) sx[i] = xq[(size_t)b * HID + i];
        __syncthreads();
        const int h4 = (tid & 7) * 4;
        const int kk = tid >> 3;                       // 0..31
        const int k0 = kk * 24;
        double m0 = 0, m1 = 0, m2 = 0, m3 = 0;
        double l0 = 0, l1 = 0, l2 = 0, l3 = 0;
        #pragma unroll 4
        for (int t = 0; t < 24; ++t) {
            const int k = k0 + t;
            const float4 wm = *(const float4*)&W_mu1[(size_t)k * H_CLUB + h4];
            const float4 wl = *(const float4*)&W_lv1[(size_t)k * H_CLUB + h4];
            const double xv = (double)sx[k];
            m0 = fma(xv, (double)wm.x, m0);
            m1 = fma(xv, (double)wm.y, m1);
            m2 = fma(xv, (double)wm.z, m2);
            m3 = fma(xv, (double)wm.w, m3);
            l0 = fma(xv, (double)wl.x, l0);
            l1 = fma(xv, (double)wl.y, l1);
            l2 = fma(xv, (double)wl.z, l2);
            l3 = fma(xv, (double)wl.w, l3);
        }
        s_mu[kk][h4 + 0] = m0; s_mu[kk][h4 + 1] = m1;
        s_mu[kk][h4 + 2] = m2; s_mu[kk][h4 + 3] = m3;
        s_lv[kk][h4 + 0] = l0; s_lv[kk][h4 + 1] = l1;
        s_lv[kk][h4 + 2] = l2; s_lv[kk][h4 + 3] = l3;
        __syncthreads();
        if (tid < H_CLUB) {
            double am = (double)b_mu1[tid], al = (double)b_lv1[tid];
            #pragma unroll
            for (int i = 0; i < 32; ++i) { am += s_mu[i][tid]; al += s_lv[i][tid]; }
            h_mu[b * H_CLUB + tid] = fmaxf((float)am, 0.f);
            h_lv[b * H_CLUB + tid] = fmaxf((float)al, 0.f);
        }
    }
}

// ---------------------------------------------------------------------------
// K4: CLUB main. UNCHANGED — summation structure frozen (absmax margin 8%).
// ---------------------------------------------------------------------------
__global__ void k_club_main(const float* __restrict__ W_mu2, const float* __restrict__ b_mu2,
                            const float* __restrict__ W_lv2, const float* __restrict__ b_lv2,
                            const float* __restrict__ h_mu, const float* __restrict__ h_lv,
                            const float* __restrict__ y_hist, const int* __restrict__ perm,
                            double* __restrict__ club_partial) {
    __shared__ float s_hmu[16 * H_CLUB];
    __shared__ float s_hlv[16 * H_CLUB];
    __shared__ int   s_perm[16];
    __shared__ double red[256];
    const int tid = threadIdx.x;
    const int c   = blockIdx.x * 256 + tid;
    const int b0  = blockIdx.y * 16;
    if (tid < 16) s_perm[tid] = perm[b0 + tid];
    for (int i = tid; i < 16 * H_CLUB; i += 256) {
        s_hmu[i] = h_mu[b0 * H_CLUB + i];
        s_hlv[i] = h_lv[b0 * H_CLUB + i];
    }
    __syncthreads();

    double total = 0.0;
    if (c < C) {
        float wm[H_CLUB], wl[H_CLUB];
        #pragma unroll
        for (int h = 0; h < H_CLUB; ++h) {
            wm[h] = W_mu2[(size_t)h * C + c];
            wl[h] = W_lv2[(size_t)h * C + c];
        }
        const float bm = b_mu2[c], bl = b_lv2[c];
        for (int bb = 0; bb < 16; ++bb) {
            float mu = bm, lv = bl;
            #pragma unroll
            for (int h = 0; h < H_CLUB; ++h) {
                mu = fmaf(s_hmu[bb * H_CLUB + h], wm[h], mu);
                lv = fmaf(s_hlv[bb * H_CLUB + h], wl[h], lv);
            }
            const float th = tanhf(lv);
            const float iv = 1.0f / (expf(th) + 1e-6f);
            const int b = b0 + bb;
            const float y  = y_hist[(size_t)b * C + c] * (1.0f / (float)L);
            const float yp = y_hist[(size_t)s_perm[bb] * C + c] * (1.0f / (float)L);
            const float dn = mu - yp;
            const float dp = mu - y;
            total += (double)(iv * (dn * dn - dp * dp));
        }
    }
    red[tid] = total;
    __syncthreads();
    for (int off = 128; off > 0; off >>= 1) {
        if (tid < off) red[tid] += red[tid + off];
        __syncthreads();
    }
    if (tid == 0) club_partial[blockIdx.y * gridDim.x + blockIdx.x] = red[0];
}

// ---------------------------------------------------------------------------
// K6 v2: final. Round-4 version was 87.8 us: tid-0 ran 64 SERIAL fp64 exp()
// software routines (no v_exp_f64 exists) plus serial 64-iter loops at
// VALUBusy 2e-4%. Now: club tree unchanged (frozen), then wave-0 computes all
// 64 T-pairs in parallel and does shuffle-tree max/sum — the 64 exps run in
// one lockstep pass. fp64 reassociation of mean0/se: ~1e-16, harmless.
// ---------------------------------------------------------------------------
__global__ void k_final(const double* __restrict__ dv, const double* __restrict__ dq,
                        const float* __restrict__ b_t1, const float* __restrict__ W_t2,
                        const float* __restrict__ b_t2, const int* __restrict__ rand_idx,
                        const double* __restrict__ club_partial,
                        float* __restrict__ out) {
    __shared__ double red[256];
    const int tid = threadIdx.x;
    double cp = 0.0;
    for (int i = tid; i < N_CLUB_PART; i += 256) cp += club_partial[i];
    red[tid] = cp;
    __syncthreads();
    for (int off = 128; off > 0; off >>= 1) {
        if (tid < off) red[tid] += red[tid + off];
        __syncthreads();
    }
    const double club_total = red[0];

    if (tid < B) {  // wave 0 only (B == 64 == wavefront size)
        const int b  = tid;
        const int rb = rand_idx[b];
        double a0 = 0.0, a1 = 0.0;
        #pragma unroll 4
        for (int j = 0; j < H_MINE; ++j) {
            const double base_v = dv[b * H_MINE + j] + (double)b_t1[j];
            const double v0 = base_v + dq[b * H_MINE + j];
            const double v1 = base_v + dq[rb * H_MINE + j];
            const double w = (double)W_t2[j];
            a0 = fma(fmax(v0, 0.0), w, a0);
            a1 = fma(fmax(v1, 0.0), w, a1);
        }
        const double T0 = a0 + (double)b_t2[0];
        const double T1 = a1 + (double)b_t2[0];

        // wave-wide fp64 shuffle reductions (all 64 lanes active, lockstep)
        double msum = T0;
        #pragma unroll
        for (int off = 32; off > 0; off >>= 1) msum += __shfl_down(msum, off, 64);
        double mx = T1;
        #pragma unroll
        for (int off = 32; off > 0; off >>= 1) mx = fmax(mx, __shfl_down(mx, off, 64));
        mx = __shfl(mx, 0, 64);                  // broadcast max
        double e = exp(T1 - mx);                 // 64 exps in one lockstep pass
        #pragma unroll
        for (int off = 32; off > 0; off >>= 1) e += __shfl_down(e, off, 64);

        if (tid == 0) {
            const double mean0 = msum * (1.0 / (double)B);
            const double lse   = mx + log(e);
            const double I_xz  = mean0 - (lse - log((double)B));
            const double I_zy  = club_total / (2.0 * (double)B);
            out[0] = (float)(I_zy - 0.1 * I_xz);
        }
    }
}

// ---------------------------------------------------------------------------
extern "C" void kernel_launch(void* const* d_in, const int* in_sizes, int n_in,
                              void* d_out, int out_size, void* d_ws, size_t ws_size,
                              hipStream_t stream) {
    const float* vit     = (const float*)d_in[0];
    const float* qformer = (const float*)d_in[1];
    const int*   label   = (const int*)d_in[2];
    const int*   perm    = (const int*)d_in[3];
    const int*   randi   = (const int*)d_in[4];
    const float* W_mu1   = (const float*)d_in[5];
    const float* b_mu1   = (const float*)d_in[6];
    const float* W_mu2   = (const float*)d_in[7];
    const float* b_mu2   = (const float*)d_in[8];
    const float* W_lv1   = (const float*)d_in[9];
    const float* b_lv1   = (const float*)d_in[10];
    const float* W_lv2   = (const float*)d_in[11];
    const float* b_lv2   = (const float*)d_in[12];
    const float* W_t1    = (const float*)d_in[13];
    const float* b_t1    = (const float*)d_in[14];
    const float* W_t2    = (const float*)d_in[15];
    const float* b_t2    = (const float*)d_in[16];

    float* ws      = (float*)d_ws;
    float* xv_sum  = ws + OFF_XVSUM;
    float* y_hist  = ws + OFF_YHIST;
    double* dv64   = (double*)(ws + OFF_DV64);
    double* dq64   = (double*)(ws + OFF_DQ64);
    float* xq      = ws + OFF_XQ;
    float* h_mu    = ws + OFF_HMU;
    float* h_lv    = ws + OFF_HLV;
    double* club_p = (double*)(ws + OFF_CLUBP);

    // Zero the accumulation buffers (xv_sum, y_hist, dv64, dq64).
    hipMemsetAsync(ws, 0, (size_t)WS_ZERO_FLOATS * sizeof(float), stream);

    k_stage_a<<<568, 256, 0, stream>>>(vit, qformer, label, xv_sum, xq, y_hist);
    k_stage_b<<<320, 256, 0, stream>>>(xv_sum, xq, W_t1, W_mu1, b_mu1, W_lv1, b_lv1,
                                       dv64, dq64, h_mu, h_lv);
    k_club_main<<<dim3(N_CLUB_BLK_X, N_CLUB_BLK_Y), 256, 0, stream>>>(
        W_mu2, b_mu2, W_lv2, b_lv2, h_mu, h_lv, y_hist, perm, club_p);
    k_final<<<1, 256, 0, stream>>>(dv64, dq64, b_t1, W_t2, b_t2, randi, club_p, (float*)d_out);
}